// Round 5
// baseline (707.018 us; speedup 1.0000x reference)
//
#include <hip/hip_runtime.h>
#include <hip/hip_bf16.h>
#include <hip/hip_fp16.h>

#define NN 50000
#define EE 800000

typedef float f32x4 __attribute__((ext_vector_type(4)));
typedef short bf16x8 __attribute__((ext_vector_type(8)));
typedef _Float16 f16x2 __attribute__((ext_vector_type(2)));

__device__ __forceinline__ unsigned short f32_to_bf16_rne(float f) {
    unsigned int u = __float_as_uint(f);
    unsigned int r = (u + 0x7FFFu + ((u >> 16) & 1u)) >> 16;
    return (unsigned short)r;
}
__device__ __forceinline__ float bf16_to_f32(unsigned short h) {
    return __uint_as_float(((unsigned int)h) << 16);
}

__device__ __forceinline__ void gl_lds16(const unsigned short* g, unsigned short* l) {
    __builtin_amdgcn_global_load_lds(
        (const __attribute__((address_space(1))) void*)g,
        (__attribute__((address_space(3))) void*)l, 16, 0, 0);
}

// ---------------------------------------------------------------------------
// CSR build
// ---------------------------------------------------------------------------
__global__ void hist_kernel(const int* __restrict__ dst, int* __restrict__ counts, int E) {
    int idx = blockIdx.x * blockDim.x + threadIdx.x;
    int stride = gridDim.x * blockDim.x;
    for (int e = idx; e < E; e += stride)
        atomicAdd(&counts[dst[e]], 1);
}

__global__ void scan_kernel(const int* __restrict__ counts, int* __restrict__ row_off, int n) {
    __shared__ int sums[1024];
    int t = threadIdx.x;
    int chunk = (n + 1023) >> 10;
    int lo = t * chunk;
    int hi = min(lo + chunk, n);
    int s = 0;
    for (int i = lo; i < hi; ++i) s += counts[i];
    sums[t] = s;
    __syncthreads();
    for (int off = 1; off < 1024; off <<= 1) {
        int v = (t >= off) ? sums[t - off] : 0;
        __syncthreads();
        sums[t] += v;
        __syncthreads();
    }
    int run = (t == 0) ? 0 : sums[t - 1];
    for (int i = lo; i < hi; ++i) { row_off[i] = run; run += counts[i]; }
    if (t == 1023) row_off[n] = sums[1023];
}

__global__ void scatter_kernel(const int* __restrict__ src, const int* __restrict__ dst,
                               const int* __restrict__ row_off, int* __restrict__ cursor,
                               int* __restrict__ esrc, int E) {
    int idx = blockIdx.x * blockDim.x + threadIdx.x;
    int stride = gridDim.x * blockDim.x;
    for (int e = idx; e < E; e += stride) {
        int d = dst[e];
        int pos = row_off[d] + atomicAdd(&cursor[d], 1);
        esrc[pos] = src[e];
    }
}

// ---------------------------------------------------------------------------
// Fused weight prep: 7 matrices -> transposed [Nc][K] bf16 hi/lo (Wl/Wr
// pairs concatenated along Nc).
// ---------------------------------------------------------------------------
__global__ void wsplit_all(const float* __restrict__ Wl1, const float* __restrict__ Wr1,
                           const float* __restrict__ Wl2, const float* __restrict__ Wr2,
                           const float* __restrict__ Wl3, const float* __restrict__ Wr3,
                           const float* __restrict__ Wlin,
                           unsigned short* __restrict__ w1h, unsigned short* __restrict__ w1l,
                           unsigned short* __restrict__ w2h, unsigned short* __restrict__ w2l,
                           unsigned short* __restrict__ w3h, unsigned short* __restrict__ w3l,
                           unsigned short* __restrict__ w4h, unsigned short* __restrict__ w4l) {
    int idx = blockIdx.x * blockDim.x + threadIdx.x;
    const float* W; unsigned short *oh, *ol; int K, Nc, roff, li;
    if (idx < 65536) {
        K = 128; Nc = 256; oh = w1h; ol = w1l;
        if (idx < 32768) { W = Wl1; li = idx; roff = 0; }
        else             { W = Wr1; li = idx - 32768; roff = 256; }
    } else if (idx < 196608) {
        K = 256; Nc = 256; oh = w2h; ol = w2l;
        if (idx < 131072) { W = Wl2; li = idx - 65536; roff = 0; }
        else              { W = Wr2; li = idx - 131072; roff = 256; }
    } else if (idx < 229376) {
        K = 256; Nc = 64; oh = w3h; ol = w3l;
        if (idx < 212992) { W = Wl3; li = idx - 196608; roff = 0; }
        else              { W = Wr3; li = idx - 212992; roff = 64; }
    } else if (idx < 233472) {
        K = 64; Nc = 64; oh = w4h; ol = w4l; W = Wlin; li = idx - 229376; roff = 0;
    } else return;
    int k = li / Nc, n = li - k * Nc;
    float v = W[li];
    unsigned short h = f32_to_bf16_rne(v);
    unsigned short l = f32_to_bf16_rne(v - bf16_to_f32(h));
    size_t o = (size_t)(roff + n) * K + k;
    oh[o] = h; ol[o] = l;
}

// ---------------------------------------------------------------------------
// Split fp32 -> bf16 hi/lo planes (for the layer-1 input x)
// ---------------------------------------------------------------------------
__global__ void split_f32(const float* __restrict__ in,
                          unsigned short* __restrict__ hi,
                          unsigned short* __restrict__ lo, int n4) {
    int i = blockIdx.x * blockDim.x + threadIdx.x;
    if (i >= n4) return;
    float4 v = *(const float4*)(in + (size_t)i * 4);
    ushort4 h = {f32_to_bf16_rne(v.x), f32_to_bf16_rne(v.y),
                 f32_to_bf16_rne(v.z), f32_to_bf16_rne(v.w)};
    ushort4 l = {f32_to_bf16_rne(v.x - bf16_to_f32(h.x)),
                 f32_to_bf16_rne(v.y - bf16_to_f32(h.y)),
                 f32_to_bf16_rne(v.z - bf16_to_f32(h.z)),
                 f32_to_bf16_rne(v.w - bf16_to_f32(h.w))};
    *(ushort4*)(hi + (size_t)i * 4) = h;
    *(ushort4*)(lo + (size_t)i * 4) = l;
}

// ---------------------------------------------------------------------------
// Plane GEMM: C[M,Nc] = A @ B. A pre-split bf16 hi/lo planes [M][K].
// B pre-split transposed [Nc][K]. One block covers ALL Nc columns (A read
// exactly once from HBM). 512 threads = 8 waves = CW col-waves x RG
// row-groups (CW*RG==8); block tile = RG*64 rows x Nc cols; each wave does
// 64x64 via 4x4 mfma_16x16x32 with 3 passes (Ah*Bh+Ah*Bl+Al*Bh).
// A staged via global_load_lds (16B DMA, zero VALU); B frags loaded
// global->reg (L2-resident).
// LDS layout: [plane][q][row][8] ushorts -> conflict-free ds_read_b128.
// ---------------------------------------------------------------------------
template <int CW, int RG>
__global__ __launch_bounds__(512) void gemm_planes(
        const unsigned short* __restrict__ Ahi, const unsigned short* __restrict__ Alo,
        const unsigned short* __restrict__ Bth, const unsigned short* __restrict__ Btl,
        int M, int Nc, int K, int splitCol,
        __half* __restrict__ outL, __half* __restrict__ outR,
        float* __restrict__ outF, const float* __restrict__ bias) {
    constexpr int RB = RG * 64;
    __shared__ __align__(16) unsigned short Alds[2 * 4 * RB * 8];

    int tid = threadIdx.x;
    int lane = tid & 63;
    int w = tid >> 6;
    int cw = w % CW, rg = w / CW;
    int l15 = lane & 15, q = lane >> 4;
    int row0 = blockIdx.x * RB;

    f32x4 acc[4][4] = {};

    for (int k0 = 0; k0 < K; k0 += 32) {
        // ---- stage A tile (both planes) via async DMA: RB*8 lane-loads ----
#pragma unroll
        for (int t = 0; t < RG; ++t) {
            int i = t * 512 + tid;              // 0 .. RB*8-1
            int p = i / (RB * 4);               // 0=hi, 1=lo
            int j = i % (RB * 4);
            int qq = j / RB;
            int r = j % RB;
            int row = row0 + r; if (row >= M) row = M - 1;
            const unsigned short* g = (p ? Alo : Ahi) + (size_t)row * K + k0 + qq * 8;
            gl_lds16(g, &Alds[(size_t)i * 8]);
        }
        // ---- B fragments: direct global->reg (L2 hits), overlap barrier ----
        bf16x8 bh[4], bl[4];
#pragma unroll
        for (int ni = 0; ni < 4; ++ni) {
            int gcol = cw * 64 + ni * 16 + l15;
            bh[ni] = *(const bf16x8*)(Bth + (size_t)gcol * K + k0 + q * 8);
            bl[ni] = *(const bf16x8*)(Btl + (size_t)gcol * K + k0 + q * 8);
        }
        __syncthreads();

        bf16x8 ah[4], al[4];
#pragma unroll
        for (int mi = 0; mi < 4; ++mi) {
            int rr = rg * 64 + mi * 16 + l15;
            ah[mi] = *(bf16x8*)&Alds[((0 * 4 + q) * RB + rr) * 8];
            al[mi] = *(bf16x8*)&Alds[((1 * 4 + q) * RB + rr) * 8];
        }
#pragma unroll
        for (int mi = 0; mi < 4; ++mi)
#pragma unroll
            for (int ni = 0; ni < 4; ++ni) {
                acc[mi][ni] = __builtin_amdgcn_mfma_f32_16x16x32_bf16(ah[mi], bh[ni], acc[mi][ni], 0, 0, 0);
                acc[mi][ni] = __builtin_amdgcn_mfma_f32_16x16x32_bf16(ah[mi], bl[ni], acc[mi][ni], 0, 0, 0);
                acc[mi][ni] = __builtin_amdgcn_mfma_f32_16x16x32_bf16(al[mi], bh[ni], acc[mi][ni], 0, 0, 0);
            }
        __syncthreads();
    }

    // ---- epilogue: C/D layout col=l15, row=q*4+reg ----
#pragma unroll
    for (int mi = 0; mi < 4; ++mi)
#pragma unroll
        for (int ni = 0; ni < 4; ++ni) {
            int gc = cw * 64 + ni * 16 + l15;
            if (outF) {
#pragma unroll
                for (int r = 0; r < 4; ++r) {
                    int gr = row0 + rg * 64 + mi * 16 + q * 4 + r;
                    if (gr < M) {
                        float v = acc[mi][ni][r];
                        if (bias) v += bias[gc];
                        outF[(size_t)gr * Nc + gc] = v;
                    }
                }
            } else {
                __half* dp = outL; int cc = gc;
                if (gc >= splitCol) { dp = outR; cc = gc - splitCol; }
#pragma unroll
                for (int r = 0; r < 4; ++r) {
                    int gr = row0 + rg * 64 + mi * 16 + q * 4 + r;
                    if (gr < M)
                        dp[(size_t)gr * splitCol + cc] = __float2half_rn(acc[mi][ni][r]);
                }
            }
        }
}

// ---------------------------------------------------------------------------
// GATv2 gather, H=4 x C=64, fp16 inputs, split-bf16 plane outputs.
// One wave per dst node. No online max (scores O(1)); unroll x2 for ILP.
// ---------------------------------------------------------------------------
__global__ __launch_bounds__(256) void gat_gather_h4(
        const __half* __restrict__ xl, const __half* __restrict__ xr,
        const float* __restrict__ att, const float* __restrict__ bias,
        const int* __restrict__ row_off, const int* __restrict__ esrc,
        unsigned short* __restrict__ out_hi, unsigned short* __restrict__ out_lo,
        int n) {
    int wave = threadIdx.x >> 6;
    int lane = threadIdx.x & 63;
    int node = blockIdx.x * (blockDim.x >> 6) + wave;
    if (node >= n) return;

    uint2 xraw = ((const uint2*)(xr + (size_t)node * 256))[lane];
    f16x2 xr01 = *(const f16x2*)&xraw.x;
    f16x2 xr23 = *(const f16x2*)&xraw.y;
    float4 atv = *(const float4*)(att + lane * 4);
    f16x2 at01 = {(_Float16)atv.x, (_Float16)atv.y};
    f16x2 at23 = {(_Float16)atv.z, (_Float16)atv.w};
    float4 bv  = *(const float4*)(bias + lane * 4);
    const f16x2 k02 = {(_Float16)0.2f, (_Float16)0.2f};

    float l0 = 0.f, l1 = 0.f;
    float4 a0 = {0.f, 0.f, 0.f, 0.f}, a1 = {0.f, 0.f, 0.f, 0.f};

    int e0 = row_off[node], e1 = row_off[node + 1];
    int e = e0;

#define H4_BODY(EIDX, ACC, LSUM)                                              \
    {                                                                         \
        int s_ = esrc[EIDX];                                                  \
        uint2 raw_ = ((const uint2*)(xl + (size_t)s_ * 256))[lane];           \
        f16x2 v01_ = *(const f16x2*)&raw_.x;                                  \
        f16x2 v23_ = *(const f16x2*)&raw_.y;                                  \
        f16x2 s01_ = v01_ + xr01;                                             \
        f16x2 s23_ = v23_ + xr23;                                             \
        f16x2 e01_ = __builtin_elementwise_max(s01_, s01_ * k02);             \
        f16x2 e23_ = __builtin_elementwise_max(s23_, s23_ * k02);             \
        float t_ = __builtin_amdgcn_fdot2(e01_, at01, 0.f, false);            \
        t_ = __builtin_amdgcn_fdot2(e23_, at23, t_, false);                   \
        t_ += __shfl_xor(t_, 1);                                              \
        t_ += __shfl_xor(t_, 2);                                              \
        t_ += __shfl_xor(t_, 4);                                              \
        t_ += __shfl_xor(t_, 8);                                              \
        float p_ = __expf(t_);                                                \
        LSUM += p_;                                                           \
        ACC.x += p_ * (float)v01_.x;                                          \
        ACC.y += p_ * (float)v01_.y;                                          \
        ACC.z += p_ * (float)v23_.x;                                          \
        ACC.w += p_ * (float)v23_.y;                                          \
    }

    for (; e + 1 < e1; e += 2) {
        H4_BODY(e, a0, l0)
        H4_BODY(e + 1, a1, l1)
    }
    if (e < e1) H4_BODY(e, a0, l0)
#undef H4_BODY

    float l = l0 + l1;
    float4 acc = {a0.x + a1.x, a0.y + a1.y, a0.z + a1.z, a0.w + a1.w};
    float inv = 1.f / (l + 1e-16f);
    float4 o;
    o.x = acc.x * inv + bv.x;
    o.y = acc.y * inv + bv.y;
    o.z = acc.z * inv + bv.z;
    o.w = acc.w * inv + bv.w;
    o.x = o.x > 0.f ? o.x : __expf(o.x) - 1.f;
    o.y = o.y > 0.f ? o.y : __expf(o.y) - 1.f;
    o.z = o.z > 0.f ? o.z : __expf(o.z) - 1.f;
    o.w = o.w > 0.f ? o.w : __expf(o.w) - 1.f;

    ushort4 h = {f32_to_bf16_rne(o.x), f32_to_bf16_rne(o.y),
                 f32_to_bf16_rne(o.z), f32_to_bf16_rne(o.w)};
    ushort4 lo4 = {f32_to_bf16_rne(o.x - bf16_to_f32(h.x)),
                   f32_to_bf16_rne(o.y - bf16_to_f32(h.y)),
                   f32_to_bf16_rne(o.z - bf16_to_f32(h.z)),
                   f32_to_bf16_rne(o.w - bf16_to_f32(h.w))};
    *(ushort4*)(out_hi + (size_t)node * 256 + lane * 4) = h;
    *(ushort4*)(out_lo + (size_t)node * 256 + lane * 4) = lo4;
}

// ---------------------------------------------------------------------------
// GATv2 gather, H=1 x C=64, fp16 inputs, split-plane outputs (no ELU).
// ---------------------------------------------------------------------------
__global__ __launch_bounds__(256) void gat_gather_h1(
        const __half* __restrict__ xl, const __half* __restrict__ xr,
        const float* __restrict__ att, const float* __restrict__ bias,
        const int* __restrict__ row_off, const int* __restrict__ esrc,
        unsigned short* __restrict__ out_hi, unsigned short* __restrict__ out_lo,
        int n) {
    int wave = threadIdx.x >> 6;
    int lane = threadIdx.x & 63;
    int node = blockIdx.x * (blockDim.x >> 6) + wave;
    if (node >= n) return;

    float xrv = __half2float(xr[(size_t)node * 64 + lane]);
    float atv = att[lane];
    float bv  = bias[lane];

    float l0 = 0.f, l1 = 0.f, a0 = 0.f, a1 = 0.f;
    int e0 = row_off[node], e1 = row_off[node + 1];
    int e = e0;

#define H1_BODY(EIDX, ACC, LSUM)                                              \
    {                                                                         \
        int s_ = esrc[EIDX];                                                  \
        float v_ = __half2float(xl[(size_t)s_ * 64 + lane]);                  \
        float sv_ = v_ + xrv;                                                 \
        float t_ = fmaxf(sv_, 0.2f * sv_) * atv;                              \
        t_ += __shfl_xor(t_, 1);                                              \
        t_ += __shfl_xor(t_, 2);                                              \
        t_ += __shfl_xor(t_, 4);                                              \
        t_ += __shfl_xor(t_, 8);                                              \
        t_ += __shfl_xor(t_, 16);                                             \
        t_ += __shfl_xor(t_, 32);                                             \
        float p_ = __expf(t_);                                                \
        LSUM += p_;                                                           \
        ACC += p_ * v_;                                                       \
    }

    for (; e + 1 < e1; e += 2) {
        H1_BODY(e, a0, l0)
        H1_BODY(e + 1, a1, l1)
    }
    if (e < e1) H1_BODY(e, a0, l0)
#undef H1_BODY

    float o = (a0 + a1) / (l0 + l1 + 1e-16f) + bv;
    unsigned short h = f32_to_bf16_rne(o);
    out_hi[(size_t)node * 64 + lane] = h;
    out_lo[(size_t)node * 64 + lane] = f32_to_bf16_rne(o - bf16_to_f32(h));
}

// ---------------------------------------------------------------------------
extern "C" void kernel_launch(void* const* d_in, const int* in_sizes, int n_in,
                              void* d_out, int out_size, void* d_ws, size_t ws_size,
                              hipStream_t stream) {
    const float* x    = (const float*)d_in[0];
    const float* Wl1  = (const float*)d_in[1];
    const float* Wr1  = (const float*)d_in[2];
    const float* att1 = (const float*)d_in[3];
    const float* b1   = (const float*)d_in[4];
    const float* Wl2  = (const float*)d_in[5];
    const float* Wr2  = (const float*)d_in[6];
    const float* att2 = (const float*)d_in[7];
    const float* b2   = (const float*)d_in[8];
    const float* Wl3  = (const float*)d_in[9];
    const float* Wr3  = (const float*)d_in[10];
    const float* att3 = (const float*)d_in[11];
    const float* b3   = (const float*)d_in[12];
    const float* Wlin = (const float*)d_in[13];
    const float* blin = (const float*)d_in[14];
    const int*   ei   = (const int*)d_in[15];
    const int* src = ei;
    const int* dst = ei + EE;

    const int N = NN, E = EE;

    // workspace layout (2-byte units for planes, all 16B-aligned)
    unsigned short* Xhi = (unsigned short*)d_ws;        // N*128
    unsigned short* Xlo = Xhi + (size_t)N * 128;        // N*128
    __half* xl          = (__half*)(Xlo + (size_t)N * 128); // N*256
    __half* xr          = xl + (size_t)N * 256;         // N*256
    unsigned short* Hhi = (unsigned short*)(xr + (size_t)N * 256); // N*256
    unsigned short* Hlo = Hhi + (size_t)N * 256;        // N*256
    unsigned short* Ghi = Hlo + (size_t)N * 256;        // N*64
    unsigned short* Glo = Ghi + (size_t)N * 64;         // N*64
    unsigned short* w1h = Glo + (size_t)N * 64;
    unsigned short* w1l = w1h + 65536;
    unsigned short* w2h = w1l + 65536;
    unsigned short* w2l = w2h + 131072;
    unsigned short* w3h = w2l + 131072;
    unsigned short* w3l = w3h + 32768;
    unsigned short* w4h = w3l + 32768;
    unsigned short* w4l = w4h + 4096;
    int* row_off = (int*)(w4l + 4096);                  // N+1
    int* tmp     = row_off + (N + 1);                   // N
    int* esrc    = tmp + N;                             // E

    // --- build CSR by dst ---
    hipMemsetAsync(tmp, 0, (size_t)N * sizeof(int), stream);
    hist_kernel<<<1024, 256, 0, stream>>>(dst, tmp, E);
    scan_kernel<<<1, 1024, 0, stream>>>(tmp, row_off, N);
    hipMemsetAsync(tmp, 0, (size_t)N * sizeof(int), stream);
    scatter_kernel<<<1024, 256, 0, stream>>>(src, dst, row_off, tmp, esrc, E);

    // --- weight transpose+split+concat; x pre-split ---
    wsplit_all<<<(233472 + 255) / 256, 256, 0, stream>>>(
        Wl1, Wr1, Wl2, Wr2, Wl3, Wr3, Wlin,
        w1h, w1l, w2h, w2l, w3h, w3l, w4h, w4l);
    split_f32<<<((N * 128 / 4) + 255) / 256, 256, 0, stream>>>(x, Xhi, Xlo, N * 128 / 4);

    int gatherBlocks = (N + 3) / 4;

    // --- layer 1: Xplanes[128] @ w1[512][128] -> xl,xr fp16 ---
    gemm_planes<8, 1><<<(N + 63) / 64, 512, 0, stream>>>(
        Xhi, Xlo, w1h, w1l, N, 512, 128, 256, xl, xr, nullptr, nullptr);
    gat_gather_h4<<<gatherBlocks, 256, 0, stream>>>(xl, xr, att1, b1, row_off, esrc, Hhi, Hlo, N);

    // --- layer 2: Hplanes[256] @ w2[512][256] -> xl,xr ---
    gemm_planes<8, 1><<<(N + 63) / 64, 512, 0, stream>>>(
        Hhi, Hlo, w2h, w2l, N, 512, 256, 256, xl, xr, nullptr, nullptr);
    gat_gather_h4<<<gatherBlocks, 256, 0, stream>>>(xl, xr, att2, b2, row_off, esrc, Hhi, Hlo, N);

    // --- layer 3: Hplanes[256] @ w3[128][256] -> xl,xr ([N][64] each) ---
    gemm_planes<2, 4><<<(N + 255) / 256, 512, 0, stream>>>(
        Hhi, Hlo, w3h, w3l, N, 128, 256, 64, xl, xr, nullptr, nullptr);
    gat_gather_h1<<<gatherBlocks, 256, 0, stream>>>(xl, xr, att3, b3, row_off, esrc, Ghi, Glo, N);

    // --- final: Gplanes[64] @ w4[64][64] + blin -> d_out fp32 ---
    gemm_planes<1, 8><<<(N + 511) / 512, 512, 0, stream>>>(
        Ghi, Glo, w4h, w4l, N, 64, 64, 64, nullptr, nullptr, (float*)d_out, blin);
}

// Round 6
// 658.264 us; speedup vs baseline: 1.0741x; 1.0741x over previous
//
#include <hip/hip_runtime.h>
#include <hip/hip_bf16.h>
#include <hip/hip_fp16.h>

#define NN 50000
#define EE 800000

typedef float f32x4 __attribute__((ext_vector_type(4)));
typedef short bf16x8 __attribute__((ext_vector_type(8)));
typedef _Float16 f16x2 __attribute__((ext_vector_type(2)));

__device__ __forceinline__ unsigned short f32_to_bf16_rne(float f) {
    unsigned int u = __float_as_uint(f);
    unsigned int r = (u + 0x7FFFu + ((u >> 16) & 1u)) >> 16;
    return (unsigned short)r;
}
__device__ __forceinline__ float bf16_to_f32(unsigned short h) {
    return __uint_as_float(((unsigned int)h) << 16);
}

__device__ __forceinline__ void gl_lds16(const unsigned short* g, unsigned short* l) {
    __builtin_amdgcn_global_load_lds(
        (const __attribute__((address_space(1))) void*)g,
        (__attribute__((address_space(3))) void*)l, 16, 0, 0);
}

// ---------------------------------------------------------------------------
// CSR build
// ---------------------------------------------------------------------------
__global__ void hist_kernel(const int* __restrict__ dst, int* __restrict__ counts, int E) {
    int idx = blockIdx.x * blockDim.x + threadIdx.x;
    int stride = gridDim.x * blockDim.x;
    for (int e = idx; e < E; e += stride)
        atomicAdd(&counts[dst[e]], 1);
}

__global__ void scan_kernel(const int* __restrict__ counts, int* __restrict__ row_off, int n) {
    __shared__ int sums[1024];
    int t = threadIdx.x;
    int chunk = (n + 1023) >> 10;
    int lo = t * chunk;
    int hi = min(lo + chunk, n);
    int s = 0;
    for (int i = lo; i < hi; ++i) s += counts[i];
    sums[t] = s;
    __syncthreads();
    for (int off = 1; off < 1024; off <<= 1) {
        int v = (t >= off) ? sums[t - off] : 0;
        __syncthreads();
        sums[t] += v;
        __syncthreads();
    }
    int run = (t == 0) ? 0 : sums[t - 1];
    for (int i = lo; i < hi; ++i) { row_off[i] = run; run += counts[i]; }
    if (t == 1023) row_off[n] = sums[1023];
}

__global__ void scatter_kernel(const int* __restrict__ src, const int* __restrict__ dst,
                               const int* __restrict__ row_off, int* __restrict__ cursor,
                               int* __restrict__ esrc, int E) {
    int idx = blockIdx.x * blockDim.x + threadIdx.x;
    int stride = gridDim.x * blockDim.x;
    for (int e = idx; e < E; e += stride) {
        int d = dst[e];
        int pos = row_off[d] + atomicAdd(&cursor[d], 1);
        esrc[pos] = src[e];
    }
}

// ---------------------------------------------------------------------------
// Fused weight prep: 7 matrices -> transposed [Nc][K] bf16 hi/lo (Wl/Wr
// pairs concatenated along Nc).
// ---------------------------------------------------------------------------
__global__ void wsplit_all(const float* __restrict__ Wl1, const float* __restrict__ Wr1,
                           const float* __restrict__ Wl2, const float* __restrict__ Wr2,
                           const float* __restrict__ Wl3, const float* __restrict__ Wr3,
                           const float* __restrict__ Wlin,
                           unsigned short* __restrict__ w1h, unsigned short* __restrict__ w1l,
                           unsigned short* __restrict__ w2h, unsigned short* __restrict__ w2l,
                           unsigned short* __restrict__ w3h, unsigned short* __restrict__ w3l,
                           unsigned short* __restrict__ w4h, unsigned short* __restrict__ w4l) {
    int idx = blockIdx.x * blockDim.x + threadIdx.x;
    const float* W; unsigned short *oh, *ol; int K, Nc, roff, li;
    if (idx < 65536) {
        K = 128; Nc = 256; oh = w1h; ol = w1l;
        if (idx < 32768) { W = Wl1; li = idx; roff = 0; }
        else             { W = Wr1; li = idx - 32768; roff = 256; }
    } else if (idx < 196608) {
        K = 256; Nc = 256; oh = w2h; ol = w2l;
        if (idx < 131072) { W = Wl2; li = idx - 65536; roff = 0; }
        else              { W = Wr2; li = idx - 131072; roff = 256; }
    } else if (idx < 229376) {
        K = 256; Nc = 64; oh = w3h; ol = w3l;
        if (idx < 212992) { W = Wl3; li = idx - 196608; roff = 0; }
        else              { W = Wr3; li = idx - 212992; roff = 64; }
    } else if (idx < 233472) {
        K = 64; Nc = 64; oh = w4h; ol = w4l; W = Wlin; li = idx - 229376; roff = 0;
    } else return;
    int k = li / Nc, n = li - k * Nc;
    float v = W[li];
    unsigned short h = f32_to_bf16_rne(v);
    unsigned short l = f32_to_bf16_rne(v - bf16_to_f32(h));
    size_t o = (size_t)(roff + n) * K + k;
    oh[o] = h; ol[o] = l;
}

// ---------------------------------------------------------------------------
// Split fp32 -> bf16 hi/lo planes (for the layer-1 input x)
// ---------------------------------------------------------------------------
__global__ void split_f32(const float* __restrict__ in,
                          unsigned short* __restrict__ hi,
                          unsigned short* __restrict__ lo, int n4) {
    int i = blockIdx.x * blockDim.x + threadIdx.x;
    if (i >= n4) return;
    float4 v = *(const float4*)(in + (size_t)i * 4);
    ushort4 h = {f32_to_bf16_rne(v.x), f32_to_bf16_rne(v.y),
                 f32_to_bf16_rne(v.z), f32_to_bf16_rne(v.w)};
    ushort4 l = {f32_to_bf16_rne(v.x - bf16_to_f32(h.x)),
                 f32_to_bf16_rne(v.y - bf16_to_f32(h.y)),
                 f32_to_bf16_rne(v.z - bf16_to_f32(h.z)),
                 f32_to_bf16_rne(v.w - bf16_to_f32(h.w))};
    *(ushort4*)(hi + (size_t)i * 4) = h;
    *(ushort4*)(lo + (size_t)i * 4) = l;
}

// ---------------------------------------------------------------------------
// Tiled plane GEMM: C[M,Nc] = A @ B.  A: pre-split bf16 hi/lo planes [M][K];
// B: pre-split transposed [Nc][K] hi/lo.  Block = 256 thr = ROWW x COLW
// waves; tile BM x BN (BM=ROWW*64, BN=COLW*64); wave does 64x64 via 4x4
// mfma_16x16x32, 3 passes (Ah*Bh+Ah*Bl+Al*Bh; Al*Bl ~2^-16 dropped).
// Both A and B staged to LDS by global_load_lds 16B DMA with hybrid cell
// order  cell = (row>>4)*64 + qq*16 + (row&15):
//   - global side: one DMA instr = 16 rows x 64B fully-used lines (coalesced)
//   - LDS side: contiguous in tid (DMA contract); ds_read_b128 frag reads
//     see 16B-stride consecutive cells (conflict-free).
// ---------------------------------------------------------------------------
template <int ROWW, int COLW>
__global__ __launch_bounds__(256) void gemm_tile(
        const unsigned short* __restrict__ Ahi, const unsigned short* __restrict__ Alo,
        const unsigned short* __restrict__ Bth, const unsigned short* __restrict__ Btl,
        int M, int Nc, int K, int splitCol,
        __half* __restrict__ outL, __half* __restrict__ outR,
        float* __restrict__ outF, const float* __restrict__ bias) {
    constexpr int BM = ROWW * 64, BN = COLW * 64;
    constexpr int ACELLS = BM * 8;   // 2 planes * 4 qq * BM rows
    constexpr int BCELLS = BN * 8;
    constexpr int TOT = ACELLS + BCELLS;
    __shared__ __align__(16) unsigned short lds[(size_t)TOT * 8];

    int tid = threadIdx.x;
    int lane = tid & 63;
    int w = tid >> 6;
    int rw = w / COLW, cw = w % COLW;
    int l15 = lane & 15, q = lane >> 4;
    int row0 = blockIdx.x * BM, col0 = blockIdx.y * BN;

    f32x4 acc[4][4] = {};

    for (int k0 = 0; k0 < K; k0 += 32) {
        // ---- stage A+B tiles via async DMA (wave-uniform branch) ----
#pragma unroll
        for (int it = 0; it < TOT / 256; ++it) {
            int i = it * 256 + tid;
            const unsigned short* g;
            if (i < ACELLS) {
                int p = i / (BM * 4);
                int j = i % (BM * 4);
                int qq = (j >> 4) & 3;
                int row = row0 + (j >> 6) * 16 + (j & 15);
                if (row >= M) row = M - 1;
                g = (p ? Alo : Ahi) + (size_t)row * K + k0 + qq * 8;
            } else {
                int i2 = i - ACELLS;
                int p = i2 / (BN * 4);
                int j = i2 % (BN * 4);
                int qq = (j >> 4) & 3;
                int col = col0 + (j >> 6) * 16 + (j & 15);
                g = (p ? Btl : Bth) + (size_t)col * K + k0 + qq * 8;
            }
            gl_lds16(g, &lds[(size_t)i * 8]);
        }
        __syncthreads();

        bf16x8 ah[4], al[4];
#pragma unroll
        for (int mi = 0; mi < 4; ++mi) {
            int cA = (rw * 4 + mi) * 64 + q * 16 + l15;
            ah[mi] = *(bf16x8*)&lds[(size_t)cA * 8];
            al[mi] = *(bf16x8*)&lds[((size_t)cA + BM * 4) * 8];
        }
#pragma unroll
        for (int ni = 0; ni < 4; ++ni) {
            int cB = ACELLS + (cw * 4 + ni) * 64 + q * 16 + l15;
            bf16x8 bh = *(bf16x8*)&lds[(size_t)cB * 8];
            bf16x8 bl = *(bf16x8*)&lds[((size_t)cB + BN * 4) * 8];
#pragma unroll
            for (int mi = 0; mi < 4; ++mi) {
                acc[mi][ni] = __builtin_amdgcn_mfma_f32_16x16x32_bf16(ah[mi], bh, acc[mi][ni], 0, 0, 0);
                acc[mi][ni] = __builtin_amdgcn_mfma_f32_16x16x32_bf16(ah[mi], bl, acc[mi][ni], 0, 0, 0);
                acc[mi][ni] = __builtin_amdgcn_mfma_f32_16x16x32_bf16(al[mi], bh, acc[mi][ni], 0, 0, 0);
            }
        }
        __syncthreads();
    }

    // ---- epilogue: C/D layout col=l15, row=q*4+reg ----
#pragma unroll
    for (int mi = 0; mi < 4; ++mi)
#pragma unroll
        for (int ni = 0; ni < 4; ++ni) {
            int gc = col0 + cw * 64 + ni * 16 + l15;
            if (outF) {
#pragma unroll
                for (int r = 0; r < 4; ++r) {
                    int gr = row0 + rw * 64 + mi * 16 + q * 4 + r;
                    if (gr < M) {
                        float v = acc[mi][ni][r];
                        if (bias) v += bias[gc];
                        outF[(size_t)gr * Nc + gc] = v;
                    }
                }
            } else {
                __half* dp = outL; int cc = gc;
                if (gc >= splitCol) { dp = outR; cc = gc - splitCol; }
#pragma unroll
                for (int r = 0; r < 4; ++r) {
                    int gr = row0 + rw * 64 + mi * 16 + q * 4 + r;
                    if (gr < M)
                        dp[(size_t)gr * splitCol + cc] = __float2half_rn(acc[mi][ni][r]);
                }
            }
        }
}

// ---------------------------------------------------------------------------
// GATv2 gather, H=4 x C=64, fp16 inputs, split-bf16 plane outputs.
// One wave per dst node. No online max (scores O(1)); unroll x2 for ILP.
// ---------------------------------------------------------------------------
__global__ __launch_bounds__(256) void gat_gather_h4(
        const __half* __restrict__ xl, const __half* __restrict__ xr,
        const float* __restrict__ att, const float* __restrict__ bias,
        const int* __restrict__ row_off, const int* __restrict__ esrc,
        unsigned short* __restrict__ out_hi, unsigned short* __restrict__ out_lo,
        int n) {
    int wave = threadIdx.x >> 6;
    int lane = threadIdx.x & 63;
    int node = blockIdx.x * (blockDim.x >> 6) + wave;
    if (node >= n) return;

    uint2 xraw = ((const uint2*)(xr + (size_t)node * 256))[lane];
    f16x2 xr01 = *(const f16x2*)&xraw.x;
    f16x2 xr23 = *(const f16x2*)&xraw.y;
    float4 atv = *(const float4*)(att + lane * 4);
    f16x2 at01 = {(_Float16)atv.x, (_Float16)atv.y};
    f16x2 at23 = {(_Float16)atv.z, (_Float16)atv.w};
    float4 bv  = *(const float4*)(bias + lane * 4);
    const f16x2 k02 = {(_Float16)0.2f, (_Float16)0.2f};

    float l0 = 0.f, l1 = 0.f;
    float4 a0 = {0.f, 0.f, 0.f, 0.f}, a1 = {0.f, 0.f, 0.f, 0.f};

    int e0 = row_off[node], e1 = row_off[node + 1];
    int e = e0;

#define H4_BODY(EIDX, ACC, LSUM)                                              \
    {                                                                         \
        int s_ = esrc[EIDX];                                                  \
        uint2 raw_ = ((const uint2*)(xl + (size_t)s_ * 256))[lane];           \
        f16x2 v01_ = *(const f16x2*)&raw_.x;                                  \
        f16x2 v23_ = *(const f16x2*)&raw_.y;                                  \
        f16x2 s01_ = v01_ + xr01;                                             \
        f16x2 s23_ = v23_ + xr23;                                             \
        f16x2 e01_ = __builtin_elementwise_max(s01_, s01_ * k02);             \
        f16x2 e23_ = __builtin_elementwise_max(s23_, s23_ * k02);             \
        float t_ = __builtin_amdgcn_fdot2(e01_, at01, 0.f, false);            \
        t_ = __builtin_amdgcn_fdot2(e23_, at23, t_, false);                   \
        t_ += __shfl_xor(t_, 1);                                              \
        t_ += __shfl_xor(t_, 2);                                              \
        t_ += __shfl_xor(t_, 4);                                              \
        t_ += __shfl_xor(t_, 8);                                              \
        float p_ = __expf(t_);                                                \
        LSUM += p_;                                                           \
        ACC.x += p_ * (float)v01_.x;                                          \
        ACC.y += p_ * (float)v01_.y;                                          \
        ACC.z += p_ * (float)v23_.x;                                          \
        ACC.w += p_ * (float)v23_.y;                                          \
    }

    for (; e + 1 < e1; e += 2) {
        H4_BODY(e, a0, l0)
        H4_BODY(e + 1, a1, l1)
    }
    if (e < e1) H4_BODY(e, a0, l0)
#undef H4_BODY

    float l = l0 + l1;
    float4 acc = {a0.x + a1.x, a0.y + a1.y, a0.z + a1.z, a0.w + a1.w};
    float inv = 1.f / (l + 1e-16f);
    float4 o;
    o.x = acc.x * inv + bv.x;
    o.y = acc.y * inv + bv.y;
    o.z = acc.z * inv + bv.z;
    o.w = acc.w * inv + bv.w;
    o.x = o.x > 0.f ? o.x : __expf(o.x) - 1.f;
    o.y = o.y > 0.f ? o.y : __expf(o.y) - 1.f;
    o.z = o.z > 0.f ? o.z : __expf(o.z) - 1.f;
    o.w = o.w > 0.f ? o.w : __expf(o.w) - 1.f;

    ushort4 h = {f32_to_bf16_rne(o.x), f32_to_bf16_rne(o.y),
                 f32_to_bf16_rne(o.z), f32_to_bf16_rne(o.w)};
    ushort4 lo4 = {f32_to_bf16_rne(o.x - bf16_to_f32(h.x)),
                   f32_to_bf16_rne(o.y - bf16_to_f32(h.y)),
                   f32_to_bf16_rne(o.z - bf16_to_f32(h.z)),
                   f32_to_bf16_rne(o.w - bf16_to_f32(h.w))};
    *(ushort4*)(out_hi + (size_t)node * 256 + lane * 4) = h;
    *(ushort4*)(out_lo + (size_t)node * 256 + lane * 4) = lo4;
}

// ---------------------------------------------------------------------------
// GATv2 gather, H=1 x C=64, fp16 inputs, split-plane outputs (no ELU).
// ---------------------------------------------------------------------------
__global__ __launch_bounds__(256) void gat_gather_h1(
        const __half* __restrict__ xl, const __half* __restrict__ xr,
        const float* __restrict__ att, const float* __restrict__ bias,
        const int* __restrict__ row_off, const int* __restrict__ esrc,
        unsigned short* __restrict__ out_hi, unsigned short* __restrict__ out_lo,
        int n) {
    int wave = threadIdx.x >> 6;
    int lane = threadIdx.x & 63;
    int node = blockIdx.x * (blockDim.x >> 6) + wave;
    if (node >= n) return;

    float xrv = __half2float(xr[(size_t)node * 64 + lane]);
    float atv = att[lane];
    float bv  = bias[lane];

    float l0 = 0.f, l1 = 0.f, a0 = 0.f, a1 = 0.f;
    int e0 = row_off[node], e1 = row_off[node + 1];
    int e = e0;

#define H1_BODY(EIDX, ACC, LSUM)                                              \
    {                                                                         \
        int s_ = esrc[EIDX];                                                  \
        float v_ = __half2float(xl[(size_t)s_ * 64 + lane]);                  \
        float sv_ = v_ + xrv;                                                 \
        float t_ = fmaxf(sv_, 0.2f * sv_) * atv;                              \
        t_ += __shfl_xor(t_, 1);                                              \
        t_ += __shfl_xor(t_, 2);                                              \
        t_ += __shfl_xor(t_, 4);                                              \
        t_ += __shfl_xor(t_, 8);                                              \
        t_ += __shfl_xor(t_, 16);                                             \
        t_ += __shfl_xor(t_, 32);                                             \
        float p_ = __expf(t_);                                                \
        LSUM += p_;                                                           \
        ACC += p_ * v_;                                                       \
    }

    for (; e + 1 < e1; e += 2) {
        H1_BODY(e, a0, l0)
        H1_BODY(e + 1, a1, l1)
    }
    if (e < e1) H1_BODY(e, a0, l0)
#undef H1_BODY

    float o = (a0 + a1) / (l0 + l1 + 1e-16f) + bv;
    unsigned short h = f32_to_bf16_rne(o);
    out_hi[(size_t)node * 64 + lane] = h;
    out_lo[(size_t)node * 64 + lane] = f32_to_bf16_rne(o - bf16_to_f32(h));
}

// ---------------------------------------------------------------------------
extern "C" void kernel_launch(void* const* d_in, const int* in_sizes, int n_in,
                              void* d_out, int out_size, void* d_ws, size_t ws_size,
                              hipStream_t stream) {
    const float* x    = (const float*)d_in[0];
    const float* Wl1  = (const float*)d_in[1];
    const float* Wr1  = (const float*)d_in[2];
    const float* att1 = (const float*)d_in[3];
    const float* b1   = (const float*)d_in[4];
    const float* Wl2  = (const float*)d_in[5];
    const float* Wr2  = (const float*)d_in[6];
    const float* att2 = (const float*)d_in[7];
    const float* b2   = (const float*)d_in[8];
    const float* Wl3  = (const float*)d_in[9];
    const float* Wr3  = (const float*)d_in[10];
    const float* att3 = (const float*)d_in[11];
    const float* b3   = (const float*)d_in[12];
    const float* Wlin = (const float*)d_in[13];
    const float* blin = (const float*)d_in[14];
    const int*   ei   = (const int*)d_in[15];
    const int* src = ei;
    const int* dst = ei + EE;

    const int N = NN, E = EE;

    // workspace layout
    unsigned short* Xhi = (unsigned short*)d_ws;        // N*128
    unsigned short* Xlo = Xhi + (size_t)N * 128;        // N*128
    __half* xl          = (__half*)(Xlo + (size_t)N * 128); // N*256
    __half* xr          = xl + (size_t)N * 256;         // N*256
    unsigned short* Hhi = (unsigned short*)(xr + (size_t)N * 256); // N*256
    unsigned short* Hlo = Hhi + (size_t)N * 256;        // N*256
    unsigned short* Ghi = Hlo + (size_t)N * 256;        // N*64
    unsigned short* Glo = Ghi + (size_t)N * 64;         // N*64
    unsigned short* w1h = Glo + (size_t)N * 64;
    unsigned short* w1l = w1h + 65536;
    unsigned short* w2h = w1l + 65536;
    unsigned short* w2l = w2h + 131072;
    unsigned short* w3h = w2l + 131072;
    unsigned short* w3l = w3h + 32768;
    unsigned short* w4h = w3l + 32768;
    unsigned short* w4l = w4h + 4096;
    int* row_off = (int*)(w4l + 4096);                  // N+1
    int* tmp     = row_off + (N + 1);                   // N
    int* esrc    = tmp + N;                             // E

    // --- build CSR by dst ---
    hipMemsetAsync(tmp, 0, (size_t)N * sizeof(int), stream);
    hist_kernel<<<1024, 256, 0, stream>>>(dst, tmp, E);
    scan_kernel<<<1, 1024, 0, stream>>>(tmp, row_off, N);
    hipMemsetAsync(tmp, 0, (size_t)N * sizeof(int), stream);
    scatter_kernel<<<1024, 256, 0, stream>>>(src, dst, row_off, tmp, esrc, E);

    // --- weight transpose+split+concat; x pre-split ---
    wsplit_all<<<(233472 + 255) / 256, 256, 0, stream>>>(
        Wl1, Wr1, Wl2, Wr2, Wl3, Wr3, Wlin,
        w1h, w1l, w2h, w2l, w3h, w3l, w4h, w4l);
    split_f32<<<((N * 128 / 4) + 255) / 256, 256, 0, stream>>>(x, Xhi, Xlo, N * 128 / 4);

    int gatherBlocks = (N + 3) / 4;
    dim3 gL1((N + 127) / 128, 4);   // 128x128 tiles, Nc=512
    dim3 gL3((N + 127) / 128, 1);   // 128x128 tile,  Nc=128
    dim3 gLin((N + 255) / 256, 1);  // 256x64 tiles,  Nc=64

    // --- layer 1: Xplanes[128] @ w1[512][128] -> xl,xr fp16 ---
    gemm_tile<2, 2><<<gL1, 256, 0, stream>>>(
        Xhi, Xlo, w1h, w1l, N, 512, 128, 256, xl, xr, nullptr, nullptr);
    gat_gather_h4<<<gatherBlocks, 256, 0, stream>>>(xl, xr, att1, b1, row_off, esrc, Hhi, Hlo, N);

    // --- layer 2: Hplanes[256] @ w2[512][256] -> xl,xr ---
    gemm_tile<2, 2><<<gL1, 256, 0, stream>>>(
        Hhi, Hlo, w2h, w2l, N, 512, 256, 256, xl, xr, nullptr, nullptr);
    gat_gather_h4<<<gatherBlocks, 256, 0, stream>>>(xl, xr, att2, b2, row_off, esrc, Hhi, Hlo, N);

    // --- layer 3: Hplanes[256] @ w3[128][256] -> xl,xr ([N][64] each) ---
    gemm_tile<2, 2><<<gL3, 256, 0, stream>>>(
        Hhi, Hlo, w3h, w3l, N, 128, 256, 64, xl, xr, nullptr, nullptr);
    gat_gather_h1<<<gatherBlocks, 256, 0, stream>>>(xl, xr, att3, b3, row_off, esrc, Ghi, Glo, N);

    // --- final: Gplanes[64] @ w4[64][64] + blin -> d_out fp32 ---
    gemm_tile<4, 1><<<gLin, 256, 0, stream>>>(
        Ghi, Glo, w4h, w4l, N, 64, 64, 64, nullptr, nullptr, (float*)d_out, blin);
}

// Round 7
// 594.711 us; speedup vs baseline: 1.1888x; 1.1069x over previous
//
#include <hip/hip_runtime.h>
#include <hip/hip_fp16.h>

#define NN 50000
#define EE 800000

typedef float f32x4 __attribute__((ext_vector_type(4)));
typedef _Float16 f16x8 __attribute__((ext_vector_type(8)));
typedef _Float16 f16x4 __attribute__((ext_vector_type(4)));
typedef _Float16 f16x2 __attribute__((ext_vector_type(2)));

// ---------------------------------------------------------------------------
// CSR build
// ---------------------------------------------------------------------------
__global__ void hist_kernel(const int* __restrict__ dst, int* __restrict__ counts, int E) {
    int idx = blockIdx.x * blockDim.x + threadIdx.x;
    int stride = gridDim.x * blockDim.x;
    for (int e = idx; e < E; e += stride)
        atomicAdd(&counts[dst[e]], 1);
}

__global__ void scan_kernel(const int* __restrict__ counts, int* __restrict__ row_off, int n) {
    __shared__ int sums[1024];
    int t = threadIdx.x;
    int chunk = (n + 1023) >> 10;
    int lo = t * chunk;
    int hi = min(lo + chunk, n);
    int s = 0;
    for (int i = lo; i < hi; ++i) s += counts[i];
    sums[t] = s;
    __syncthreads();
    for (int off = 1; off < 1024; off <<= 1) {
        int v = (t >= off) ? sums[t - off] : 0;
        __syncthreads();
        sums[t] += v;
        __syncthreads();
    }
    int run = (t == 0) ? 0 : sums[t - 1];
    for (int i = lo; i < hi; ++i) { row_off[i] = run; run += counts[i]; }
    if (t == 1023) row_off[n] = sums[1023];
}

__global__ void scatter_kernel(const int* __restrict__ src, const int* __restrict__ dst,
                               const int* __restrict__ row_off, int* __restrict__ cursor,
                               int* __restrict__ esrc, int E) {
    int idx = blockIdx.x * blockDim.x + threadIdx.x;
    int stride = gridDim.x * blockDim.x;
    for (int e = idx; e < E; e += stride) {
        int d = dst[e];
        int pos = row_off[d] + atomicAdd(&cursor[d], 1);
        esrc[pos] = src[e];
    }
}

// ---------------------------------------------------------------------------
// Weight prep: 7 fp32 matrices -> transposed fp16 [Nc][K] (Wl/Wr pairs
// concatenated along Nc). Single pass, no hi/lo split.
// ---------------------------------------------------------------------------
__global__ void wconv_all(const float* __restrict__ Wl1, const float* __restrict__ Wr1,
                          const float* __restrict__ Wl2, const float* __restrict__ Wr2,
                          const float* __restrict__ Wl3, const float* __restrict__ Wr3,
                          const float* __restrict__ Wlin,
                          __half* __restrict__ w1, __half* __restrict__ w2,
                          __half* __restrict__ w3, __half* __restrict__ w4) {
    int idx = blockIdx.x * blockDim.x + threadIdx.x;
    const float* W; __half* o; int K, Nc, roff, li;
    if (idx < 65536) {
        K = 128; Nc = 256; o = w1;
        if (idx < 32768) { W = Wl1; li = idx; roff = 0; }
        else             { W = Wr1; li = idx - 32768; roff = 256; }
    } else if (idx < 196608) {
        K = 256; Nc = 256; o = w2;
        if (idx < 131072) { W = Wl2; li = idx - 65536; roff = 0; }
        else              { W = Wr2; li = idx - 131072; roff = 256; }
    } else if (idx < 229376) {
        K = 256; Nc = 64; o = w3;
        if (idx < 212992) { W = Wl3; li = idx - 196608; roff = 0; }
        else              { W = Wr3; li = idx - 212992; roff = 64; }
    } else if (idx < 233472) {
        K = 64; Nc = 64; o = w4; W = Wlin; li = idx - 229376; roff = 0;
    } else return;
    int k = li / Nc, n = li - k * Nc;
    o[(size_t)(roff + n) * K + k] = __float2half_rn(W[li]);
}

// ---------------------------------------------------------------------------
// fp32 -> fp16 (layer-1 input x)
// ---------------------------------------------------------------------------
__global__ void xconv(const float* __restrict__ in, __half* __restrict__ out, int n4) {
    int i = blockIdx.x * blockDim.x + threadIdx.x;
    if (i >= n4) return;
    float4 v = *(const float4*)(in + (size_t)i * 4);
    f16x4 h = {(_Float16)v.x, (_Float16)v.y, (_Float16)v.z, (_Float16)v.w};
    *(f16x4*)((_Float16*)out + (size_t)i * 4) = h;
}

// ---------------------------------------------------------------------------
// Weight-stationary tall-skinny GEMM: C[M,Nc] = A[M,K] @ Bt[Nc,K]^T, fp16
// inputs, fp32 accum. NO LDS, NO barriers.
//   - Each wave keeps its 64-col B fragments for ALL of K in VGPRs
//     (KS x 4 x f16x8), loaded once per block from L2.
//   - A loaded global->reg directly in MFMA A-layout (16 full 64B lines per
//     b128 load: lanes {l,l+16,l+32,l+48} cover one row's 64B).
//   - Grid-stride over 64-row tiles, manual A double-buffer (prefetch t+1
//     during MFMA of t).
// Block = COLG*4 waves: wave w -> row-slot rs=w&3 (16 rows), col-group
// cg=w>>2 (64 cols). Block tile = 64 rows x COLG*64 cols per step.
// Output: dual fp16 split at splitCol (xl/xr), or fp32 + bias (outF).
// ---------------------------------------------------------------------------
template <int KS, int COLG>
__global__ __launch_bounds__(COLG * 256) void gemm_ws(
        const __half* __restrict__ A, const __half* __restrict__ Bt,
        int M, int nTiles, int Nc, int splitCol,
        __half* __restrict__ outL, __half* __restrict__ outR,
        float* __restrict__ outF, const float* __restrict__ bias) {
    constexpr int K = KS * 32;
    int tid = threadIdx.x;
    int lane = tid & 63;
    int w = tid >> 6;
    int rs = w & 3;
    int cg = w >> 2;
    int l15 = lane & 15, q = lane >> 4;
    int colbase = blockIdx.y * (COLG * 64) + cg * 64;

    const _Float16* Ap = (const _Float16*)A;
    const _Float16* Bp = (const _Float16*)Bt;

    // ---- B fragments, whole K, resident in registers ----
    f16x8 bfrag[KS][4];
#pragma unroll
    for (int ks = 0; ks < KS; ++ks)
#pragma unroll
        for (int ni = 0; ni < 4; ++ni)
            bfrag[ks][ni] = *(const f16x8*)(Bp + (size_t)(colbase + ni * 16 + l15) * K + ks * 32 + q * 8);

    int tile = blockIdx.x;
    if (tile >= nTiles) return;

    f16x8 afrag[KS];
    {
        int row = tile * 64 + rs * 16 + l15;
        if (row >= M) row = M - 1;
        const _Float16* ap = Ap + (size_t)row * K + q * 8;
#pragma unroll
        for (int ks = 0; ks < KS; ++ks) afrag[ks] = *(const f16x8*)(ap + ks * 32);
    }

    while (true) {
        int next = tile + gridDim.x;
        bool has = (next < nTiles);
        f16x8 anext[KS];
        if (has) {
            int row = next * 64 + rs * 16 + l15;
            if (row >= M) row = M - 1;
            const _Float16* ap = Ap + (size_t)row * K + q * 8;
#pragma unroll
            for (int ks = 0; ks < KS; ++ks) anext[ks] = *(const f16x8*)(ap + ks * 32);
        }

        f32x4 acc[4] = {};
#pragma unroll
        for (int ks = 0; ks < KS; ++ks)
#pragma unroll
            for (int ni = 0; ni < 4; ++ni)
                acc[ni] = __builtin_amdgcn_mfma_f32_16x16x32_f16(afrag[ks], bfrag[ks][ni], acc[ni], 0, 0, 0);

        // ---- epilogue: C/D layout col=l15, row=q*4+r ----
#pragma unroll
        for (int ni = 0; ni < 4; ++ni) {
            int gc = colbase + ni * 16 + l15;
            if (outF) {
                float bv = bias ? bias[gc] : 0.f;
#pragma unroll
                for (int r = 0; r < 4; ++r) {
                    int gr = tile * 64 + rs * 16 + q * 4 + r;
                    if (gr < M) outF[(size_t)gr * Nc + gc] = acc[ni][r] + bv;
                }
            } else {
                __half* dp = outL; int cc = gc;
                if (gc >= splitCol) { dp = outR; cc = gc - splitCol; }
#pragma unroll
                for (int r = 0; r < 4; ++r) {
                    int gr = tile * 64 + rs * 16 + q * 4 + r;
                    if (gr < M) dp[(size_t)gr * splitCol + cc] = __float2half_rn(acc[ni][r]);
                }
            }
        }
        if (!has) break;
#pragma unroll
        for (int ks = 0; ks < KS; ++ks) afrag[ks] = anext[ks];
        tile = next;
    }
}

// ---------------------------------------------------------------------------
// GATv2 gather, H=4 x C=64, fp16 in, fp16 out (ELU applied).
// One wave per dst node; no online max (scores O(1)); unroll x2 for ILP.
// ---------------------------------------------------------------------------
__global__ __launch_bounds__(256) void gat_gather_h4(
        const __half* __restrict__ xl, const __half* __restrict__ xr,
        const float* __restrict__ att, const float* __restrict__ bias,
        const int* __restrict__ row_off, const int* __restrict__ esrc,
        __half* __restrict__ out, int n) {
    int wave = threadIdx.x >> 6;
    int lane = threadIdx.x & 63;
    int node = blockIdx.x * (blockDim.x >> 6) + wave;
    if (node >= n) return;

    uint2 xraw = ((const uint2*)(xr + (size_t)node * 256))[lane];
    f16x2 xr01 = *(const f16x2*)&xraw.x;
    f16x2 xr23 = *(const f16x2*)&xraw.y;
    float4 atv = *(const float4*)(att + lane * 4);
    f16x2 at01 = {(_Float16)atv.x, (_Float16)atv.y};
    f16x2 at23 = {(_Float16)atv.z, (_Float16)atv.w};
    float4 bv  = *(const float4*)(bias + lane * 4);
    const f16x2 k02 = {(_Float16)0.2f, (_Float16)0.2f};

    float l0 = 0.f, l1 = 0.f;
    float4 a0 = {0.f, 0.f, 0.f, 0.f}, a1 = {0.f, 0.f, 0.f, 0.f};

    int e0 = row_off[node], e1 = row_off[node + 1];
    int e = e0;

#define H4_BODY(EIDX, ACC, LSUM)                                              \
    {                                                                         \
        int s_ = esrc[EIDX];                                                  \
        uint2 raw_ = ((const uint2*)(xl + (size_t)s_ * 256))[lane];           \
        f16x2 v01_ = *(const f16x2*)&raw_.x;                                  \
        f16x2 v23_ = *(const f16x2*)&raw_.y;                                  \
        f16x2 s01_ = v01_ + xr01;                                             \
        f16x2 s23_ = v23_ + xr23;                                             \
        f16x2 e01_ = __builtin_elementwise_max(s01_, s01_ * k02);             \
        f16x2 e23_ = __builtin_elementwise_max(s23_, s23_ * k02);             \
        float t_ = __builtin_amdgcn_fdot2(e01_, at01, 0.f, false);            \
        t_ = __builtin_amdgcn_fdot2(e23_, at23, t_, false);                   \
        t_ += __shfl_xor(t_, 1);                                              \
        t_ += __shfl_xor(t_, 2);                                              \
        t_ += __shfl_xor(t_, 4);                                              \
        t_ += __shfl_xor(t_, 8);                                              \
        float p_ = __expf(t_);                                                \
        LSUM += p_;                                                           \
        ACC.x += p_ * (float)v01_.x;                                          \
        ACC.y += p_ * (float)v01_.y;                                          \
        ACC.z += p_ * (float)v23_.x;                                          \
        ACC.w += p_ * (float)v23_.y;                                          \
    }

    for (; e + 1 < e1; e += 2) {
        H4_BODY(e, a0, l0)
        H4_BODY(e + 1, a1, l1)
    }
    if (e < e1) H4_BODY(e, a0, l0)
#undef H4_BODY

    float l = l0 + l1;
    float4 acc = {a0.x + a1.x, a0.y + a1.y, a0.z + a1.z, a0.w + a1.w};
    float inv = 1.f / (l + 1e-16f);
    float4 o;
    o.x = acc.x * inv + bv.x;
    o.y = acc.y * inv + bv.y;
    o.z = acc.z * inv + bv.z;
    o.w = acc.w * inv + bv.w;
    o.x = o.x > 0.f ? o.x : __expf(o.x) - 1.f;
    o.y = o.y > 0.f ? o.y : __expf(o.y) - 1.f;
    o.z = o.z > 0.f ? o.z : __expf(o.z) - 1.f;
    o.w = o.w > 0.f ? o.w : __expf(o.w) - 1.f;

    f16x4 ov = {(_Float16)o.x, (_Float16)o.y, (_Float16)o.z, (_Float16)o.w};
    *(f16x4*)((_Float16*)out + (size_t)node * 256 + lane * 4) = ov;
}

// ---------------------------------------------------------------------------
// GATv2 gather, H=1 x C=64, fp16 in, fp16 out (no ELU).
// ---------------------------------------------------------------------------
__global__ __launch_bounds__(256) void gat_gather_h1(
        const __half* __restrict__ xl, const __half* __restrict__ xr,
        const float* __restrict__ att, const float* __restrict__ bias,
        const int* __restrict__ row_off, const int* __restrict__ esrc,
        __half* __restrict__ out, int n) {
    int wave = threadIdx.x >> 6;
    int lane = threadIdx.x & 63;
    int node = blockIdx.x * (blockDim.x >> 6) + wave;
    if (node >= n) return;

    float xrv = __half2float(xr[(size_t)node * 64 + lane]);
    float atv = att[lane];
    float bv  = bias[lane];

    float l0 = 0.f, l1 = 0.f, a0 = 0.f, a1 = 0.f;
    int e0 = row_off[node], e1 = row_off[node + 1];
    int e = e0;

#define H1_BODY(EIDX, ACC, LSUM)                                              \
    {                                                                         \
        int s_ = esrc[EIDX];                                                  \
        float v_ = __half2float(xl[(size_t)s_ * 64 + lane]);                  \
        float sv_ = v_ + xrv;                                                 \
        float t_ = fmaxf(sv_, 0.2f * sv_) * atv;                              \
        t_ += __shfl_xor(t_, 1);                                              \
        t_ += __shfl_xor(t_, 2);                                              \
        t_ += __shfl_xor(t_, 4);                                              \
        t_ += __shfl_xor(t_, 8);                                              \
        t_ += __shfl_xor(t_, 16);                                             \
        t_ += __shfl_xor(t_, 32);                                             \
        float p_ = __expf(t_);                                                \
        LSUM += p_;                                                           \
        ACC += p_ * v_;                                                       \
    }

    for (; e + 1 < e1; e += 2) {
        H1_BODY(e, a0, l0)
        H1_BODY(e + 1, a1, l1)
    }
    if (e < e1) H1_BODY(e, a0, l0)
#undef H1_BODY

    float o = (a0 + a1) / (l0 + l1 + 1e-16f) + bv;
    out[(size_t)node * 64 + lane] = __float2half_rn(o);
}

// ---------------------------------------------------------------------------
extern "C" void kernel_launch(void* const* d_in, const int* in_sizes, int n_in,
                              void* d_out, int out_size, void* d_ws, size_t ws_size,
                              hipStream_t stream) {
    const float* x    = (const float*)d_in[0];
    const float* Wl1  = (const float*)d_in[1];
    const float* Wr1  = (const float*)d_in[2];
    const float* att1 = (const float*)d_in[3];
    const float* b1   = (const float*)d_in[4];
    const float* Wl2  = (const float*)d_in[5];
    const float* Wr2  = (const float*)d_in[6];
    const float* att2 = (const float*)d_in[7];
    const float* b2   = (const float*)d_in[8];
    const float* Wl3  = (const float*)d_in[9];
    const float* Wr3  = (const float*)d_in[10];
    const float* att3 = (const float*)d_in[11];
    const float* b3   = (const float*)d_in[12];
    const float* Wlin = (const float*)d_in[13];
    const float* blin = (const float*)d_in[14];
    const int*   ei   = (const int*)d_in[15];
    const int* src = ei;
    const int* dst = ei + EE;

    const int N = NN, E = EE;

    // workspace layout (fp16 arrays, all 16B-aligned)
    __half* xf = (__half*)d_ws;                 // N*128
    __half* xl = xf + (size_t)N * 128;          // N*256
    __half* xr = xl + (size_t)N * 256;          // N*256
    __half* H  = xr + (size_t)N * 256;          // N*256
    __half* G  = H + (size_t)N * 256;           // N*64
    __half* w1 = G + (size_t)N * 64;            // 65536  [512][128]
    __half* w2 = w1 + 65536;                    // 131072 [512][256]
    __half* w3 = w2 + 131072;                   // 32768  [128][256]
    __half* w4 = w3 + 32768;                    // 4096   [64][64]
    int* row_off = (int*)(w4 + 4096);           // N+1
    int* tmp     = row_off + (N + 1);           // N
    int* esrc    = tmp + N;                     // E

    // --- build CSR by dst ---
    hipMemsetAsync(tmp, 0, (size_t)N * sizeof(int), stream);
    hist_kernel<<<1024, 256, 0, stream>>>(dst, tmp, E);
    scan_kernel<<<1, 1024, 0, stream>>>(tmp, row_off, N);
    hipMemsetAsync(tmp, 0, (size_t)N * sizeof(int), stream);
    scatter_kernel<<<1024, 256, 0, stream>>>(src, dst, row_off, tmp, esrc, E);

    // --- weight transpose to fp16; x -> fp16 ---
    wconv_all<<<(233472 + 255) / 256, 256, 0, stream>>>(
        Wl1, Wr1, Wl2, Wr2, Wl3, Wr3, Wlin, w1, w2, w3, w4);
    xconv<<<((N * 128 / 4) + 255) / 256, 256, 0, stream>>>(x, xf, N * 128 / 4);

    int nTiles = (N + 63) / 64;
    int gatherBlocks = (N + 3) / 4;

    // --- layer 1: xf[128] @ w1 -> xl,xr fp16 ---
    gemm_ws<4, 2><<<dim3(64, 4), 512, 0, stream>>>(
        xf, w1, N, nTiles, 512, 256, xl, xr, nullptr, nullptr);
    gat_gather_h4<<<gatherBlocks, 256, 0, stream>>>(xl, xr, att1, b1, row_off, esrc, H, N);

    // --- layer 2: H[256] @ w2 -> xl,xr ---
    gemm_ws<8, 2><<<dim3(64, 4), 512, 0, stream>>>(
        H, w2, N, nTiles, 512, 256, xl, xr, nullptr, nullptr);
    gat_gather_h4<<<gatherBlocks, 256, 0, stream>>>(xl, xr, att2, b2, row_off, esrc, H, N);

    // --- layer 3: H[256] @ w3 -> xl,xr ([N][64] each) ---
    gemm_ws<8, 2><<<dim3(256, 1), 512, 0, stream>>>(
        H, w3, N, nTiles, 128, 64, xl, xr, nullptr, nullptr);
    gat_gather_h1<<<gatherBlocks, 256, 0, stream>>>(xl, xr, att3, b3, row_off, esrc, G, N);

    // --- final: G[64] @ w4 + blin -> d_out fp32 ---
    gemm_ws<2, 1><<<dim3(512, 1), 256, 0, stream>>>(
        G, w4, N, nTiles, 64, 64, nullptr, nullptr, (float*)d_out, blin);
}

// Round 8
// 570.400 us; speedup vs baseline: 1.2395x; 1.0426x over previous
//
#include <hip/hip_runtime.h>
#include <hip/hip_fp16.h>

#define NN 50000
#define EE 800000

typedef float f32x4 __attribute__((ext_vector_type(4)));
typedef float f32x2 __attribute__((ext_vector_type(2)));
typedef _Float16 f16x8 __attribute__((ext_vector_type(8)));
typedef _Float16 f16x4 __attribute__((ext_vector_type(4)));
typedef _Float16 f16x2 __attribute__((ext_vector_type(2)));

// ---------------------------------------------------------------------------
// CSR build
// ---------------------------------------------------------------------------
__global__ void hist_kernel(const int* __restrict__ dst, int* __restrict__ counts, int E) {
    int idx = blockIdx.x * blockDim.x + threadIdx.x;
    int stride = gridDim.x * blockDim.x;
    for (int e = idx; e < E; e += stride)
        atomicAdd(&counts[dst[e]], 1);
}

__global__ void scan_kernel(const int* __restrict__ counts, int* __restrict__ row_off, int n) {
    __shared__ int sums[1024];
    int t = threadIdx.x;
    int chunk = (n + 1023) >> 10;
    int lo = t * chunk;
    int hi = min(lo + chunk, n);
    int s = 0;
    for (int i = lo; i < hi; ++i) s += counts[i];
    sums[t] = s;
    __syncthreads();
    for (int off = 1; off < 1024; off <<= 1) {
        int v = (t >= off) ? sums[t - off] : 0;
        __syncthreads();
        sums[t] += v;
        __syncthreads();
    }
    int run = (t == 0) ? 0 : sums[t - 1];
    for (int i = lo; i < hi; ++i) { row_off[i] = run; run += counts[i]; }
    if (t == 1023) row_off[n] = sums[1023];
}

__global__ void scatter_kernel(const int* __restrict__ src, const int* __restrict__ dst,
                               const int* __restrict__ row_off, int* __restrict__ cursor,
                               int* __restrict__ esrc, int E) {
    int idx = blockIdx.x * blockDim.x + threadIdx.x;
    int stride = gridDim.x * blockDim.x;
    for (int e = idx; e < E; e += stride) {
        int d = dst[e];
        int pos = row_off[d] + atomicAdd(&cursor[d], 1);
        esrc[pos] = src[e];
    }
}

// ---------------------------------------------------------------------------
// Fused prep: weights -> transposed fp16 [Nc][K] (Wl/Wr concat), x -> fp16.
// idx < 233472: weight element; else: one float4 of x.
// ---------------------------------------------------------------------------
__global__ void prep_all(const float* __restrict__ Wl1, const float* __restrict__ Wr1,
                         const float* __restrict__ Wl2, const float* __restrict__ Wr2,
                         const float* __restrict__ Wl3, const float* __restrict__ Wr3,
                         const float* __restrict__ Wlin,
                         __half* __restrict__ w1, __half* __restrict__ w2,
                         __half* __restrict__ w3, __half* __restrict__ w4,
                         const float* __restrict__ x, __half* __restrict__ xf, int n4x) {
    int idx = blockIdx.x * blockDim.x + threadIdx.x;
    if (idx < 233472) {
        const float* W; __half* o; int K, Nc, roff, li;
        if (idx < 65536) {
            K = 128; Nc = 256; o = w1;
            if (idx < 32768) { W = Wl1; li = idx; roff = 0; }
            else             { W = Wr1; li = idx - 32768; roff = 256; }
        } else if (idx < 196608) {
            K = 256; Nc = 256; o = w2;
            if (idx < 131072) { W = Wl2; li = idx - 65536; roff = 0; }
            else              { W = Wr2; li = idx - 131072; roff = 256; }
        } else if (idx < 229376) {
            K = 256; Nc = 64; o = w3;
            if (idx < 212992) { W = Wl3; li = idx - 196608; roff = 0; }
            else              { W = Wr3; li = idx - 212992; roff = 64; }
        } else {
            K = 64; Nc = 64; o = w4; W = Wlin; li = idx - 229376; roff = 0;
        }
        int k = li / Nc, n = li - k * Nc;
        o[(size_t)(roff + n) * K + k] = __float2half_rn(W[li]);
    } else {
        int xi = idx - 233472;
        if (xi < n4x) {
            float4 v = *(const float4*)(x + (size_t)xi * 4);
            f16x4 h = {(_Float16)v.x, (_Float16)v.y, (_Float16)v.z, (_Float16)v.w};
            *(f16x4*)((_Float16*)xf + (size_t)xi * 4) = h;
        }
    }
}

// ---------------------------------------------------------------------------
// Weight-stationary tall-skinny GEMM (unchanged from R7): no LDS, no
// barriers, B resident in VGPRs for all K, A global->reg in MFMA layout,
// grid-stride tiles with A double-buffer.
// ---------------------------------------------------------------------------
template <int KS, int COLG>
__global__ __launch_bounds__(COLG * 256) void gemm_ws(
        const __half* __restrict__ A, const __half* __restrict__ Bt,
        int M, int nTiles, int Nc, int splitCol,
        __half* __restrict__ outL, __half* __restrict__ outR,
        float* __restrict__ outF, const float* __restrict__ bias) {
    constexpr int K = KS * 32;
    int tid = threadIdx.x;
    int lane = tid & 63;
    int w = tid >> 6;
    int rs = w & 3;
    int cg = w >> 2;
    int l15 = lane & 15, q = lane >> 4;
    int colbase = blockIdx.y * (COLG * 64) + cg * 64;

    const _Float16* Ap = (const _Float16*)A;
    const _Float16* Bp = (const _Float16*)Bt;

    f16x8 bfrag[KS][4];
#pragma unroll
    for (int ks = 0; ks < KS; ++ks)
#pragma unroll
        for (int ni = 0; ni < 4; ++ni)
            bfrag[ks][ni] = *(const f16x8*)(Bp + (size_t)(colbase + ni * 16 + l15) * K + ks * 32 + q * 8);

    int tile = blockIdx.x;
    if (tile >= nTiles) return;

    f16x8 afrag[KS];
    {
        int row = tile * 64 + rs * 16 + l15;
        if (row >= M) row = M - 1;
        const _Float16* ap = Ap + (size_t)row * K + q * 8;
#pragma unroll
        for (int ks = 0; ks < KS; ++ks) afrag[ks] = *(const f16x8*)(ap + ks * 32);
    }

    while (true) {
        int next = tile + gridDim.x;
        bool has = (next < nTiles);
        f16x8 anext[KS];
        if (has) {
            int row = next * 64 + rs * 16 + l15;
            if (row >= M) row = M - 1;
            const _Float16* ap = Ap + (size_t)row * K + q * 8;
#pragma unroll
            for (int ks = 0; ks < KS; ++ks) anext[ks] = *(const f16x8*)(ap + ks * 32);
        }

        f32x4 acc[4] = {};
#pragma unroll
        for (int ks = 0; ks < KS; ++ks)
#pragma unroll
            for (int ni = 0; ni < 4; ++ni)
                acc[ni] = __builtin_amdgcn_mfma_f32_16x16x32_f16(afrag[ks], bfrag[ks][ni], acc[ni], 0, 0, 0);

#pragma unroll
        for (int ni = 0; ni < 4; ++ni) {
            int gc = colbase + ni * 16 + l15;
            if (outF) {
                float bv = bias ? bias[gc] : 0.f;
#pragma unroll
                for (int r = 0; r < 4; ++r) {
                    int gr = tile * 64 + rs * 16 + q * 4 + r;
                    if (gr < M) outF[(size_t)gr * Nc + gc] = acc[ni][r] + bv;
                }
            } else {
                __half* dp = outL; int cc = gc;
                if (gc >= splitCol) { dp = outR; cc = gc - splitCol; }
#pragma unroll
                for (int r = 0; r < 4; ++r) {
                    int gr = tile * 64 + rs * 16 + q * 4 + r;
                    if (gr < M) dp[(size_t)gr * splitCol + cc] = __float2half_rn(acc[ni][r]);
                }
            }
        }
        if (!has) break;
#pragma unroll
        for (int ks = 0; ks < KS; ++ks) afrag[ks] = anext[ks];
        tile = next;
    }
}

// ---------------------------------------------------------------------------
// GATv2 gather, H=4 x C=64, fp16 in/out. One wave per dst node,
// TWO edges per wave-pass: lanes 0-31 -> edge e, lanes 32-63 -> edge e+1.
// Lane half h=l>>5, group j=l&31: 8 channels j*8..+7 (16B loads).
// att pre-scaled by log2(e) -> exp2f. No online max. Unroll x2 (4 edges
// in flight). Tail masked via clamp + p=0.
// ---------------------------------------------------------------------------
__global__ __launch_bounds__(256) void gat_gather_h4(
        const __half* __restrict__ xl, const __half* __restrict__ xr,
        const float* __restrict__ att, const float* __restrict__ bias,
        const int* __restrict__ row_off, const int* __restrict__ esrc,
        __half* __restrict__ out, int n) {
    const float LOG2E = 1.44269504f;
    int wave = threadIdx.x >> 6;
    int lane = threadIdx.x & 63;
    int node = blockIdx.x * 4 + wave;
    if (node >= n) return;
    int half = lane >> 5;
    int j = lane & 31;

    uint4 xraw = ((const uint4*)(xr + (size_t)node * 256))[j];
    f16x2 xrv[4] = {*(const f16x2*)&xraw.x, *(const f16x2*)&xraw.y,
                    *(const f16x2*)&xraw.z, *(const f16x2*)&xraw.w};
    float4 aA = *(const float4*)(att + j * 8);
    float4 aB = *(const float4*)(att + j * 8 + 4);
    f16x2 atv[4] = {{(_Float16)(aA.x * LOG2E), (_Float16)(aA.y * LOG2E)},
                    {(_Float16)(aA.z * LOG2E), (_Float16)(aA.w * LOG2E)},
                    {(_Float16)(aB.x * LOG2E), (_Float16)(aB.y * LOG2E)},
                    {(_Float16)(aB.z * LOG2E), (_Float16)(aB.w * LOG2E)}};
    const f16x2 k02 = {(_Float16)0.2f, (_Float16)0.2f};

    f32x2 acc0[4] = {}, acc1[4] = {};
    float l0 = 0.f, l1 = 0.f;

    int e0 = row_off[node], e1 = row_off[node + 1];
    int elast = e1 - 1;

#define H4_BODY(EBASE, ACC, LSUM)                                             \
    {                                                                         \
        int idx_ = EBASE + half;                                              \
        int s_ = esrc[min(idx_, elast)];                                      \
        uint4 raw_ = ((const uint4*)(xl + (size_t)s_ * 256))[j];              \
        f16x2 v0_ = *(const f16x2*)&raw_.x;                                   \
        f16x2 v1_ = *(const f16x2*)&raw_.y;                                   \
        f16x2 v2_ = *(const f16x2*)&raw_.z;                                   \
        f16x2 v3_ = *(const f16x2*)&raw_.w;                                   \
        f16x2 s0_ = v0_ + xrv[0], s1_ = v1_ + xrv[1];                         \
        f16x2 s2_ = v2_ + xrv[2], s3_ = v3_ + xrv[3];                         \
        f16x2 r0_ = __builtin_elementwise_max(s0_, s0_ * k02);                \
        f16x2 r1_ = __builtin_elementwise_max(s1_, s1_ * k02);                \
        f16x2 r2_ = __builtin_elementwise_max(s2_, s2_ * k02);                \
        f16x2 r3_ = __builtin_elementwise_max(s3_, s3_ * k02);                \
        float t_ = __builtin_amdgcn_fdot2(r0_, atv[0], 0.f, false);           \
        t_ = __builtin_amdgcn_fdot2(r1_, atv[1], t_, false);                  \
        t_ = __builtin_amdgcn_fdot2(r2_, atv[2], t_, false);                  \
        t_ = __builtin_amdgcn_fdot2(r3_, atv[3], t_, false);                  \
        t_ += __shfl_xor(t_, 1);                                              \
        t_ += __shfl_xor(t_, 2);                                              \
        t_ += __shfl_xor(t_, 4);                                              \
        float p_ = exp2f(t_);                                                 \
        p_ = (idx_ < e1) ? p_ : 0.f;                                          \
        LSUM += p_;                                                           \
        f32x2 pp_ = {p_, p_};                                                 \
        ACC[0] += pp_ * (f32x2){(float)v0_.x, (float)v0_.y};                  \
        ACC[1] += pp_ * (f32x2){(float)v1_.x, (float)v1_.y};                  \
        ACC[2] += pp_ * (f32x2){(float)v2_.x, (float)v2_.y};                  \
        ACC[3] += pp_ * (f32x2){(float)v3_.x, (float)v3_.y};                  \
    }

    for (int e = e0; e < e1; e += 4) {
        H4_BODY(e, acc0, l0)
        if (e + 2 < e1) H4_BODY(e + 2, acc1, l1)
    }
#undef H4_BODY

    f32x2 acc[4];
#pragma unroll
    for (int k = 0; k < 4; ++k) acc[k] = acc0[k] + acc1[k];
    float L = l0 + l1;
    // combine the two half-waves
#pragma unroll
    for (int k = 0; k < 4; ++k) {
        acc[k].x += __shfl_xor(acc[k].x, 32);
        acc[k].y += __shfl_xor(acc[k].y, 32);
    }
    L += __shfl_xor(L, 32);

    float inv = 1.f / (L + 1e-16f);
    float4 bvA = *(const float4*)(bias + j * 8);
    float4 bvB = *(const float4*)(bias + j * 8 + 4);
    float o[8] = {acc[0].x * inv + bvA.x, acc[0].y * inv + bvA.y,
                  acc[1].x * inv + bvA.z, acc[1].y * inv + bvA.w,
                  acc[2].x * inv + bvB.x, acc[2].y * inv + bvB.y,
                  acc[3].x * inv + bvB.z, acc[3].y * inv + bvB.w};
    f16x8 ov;
#pragma unroll
    for (int k = 0; k < 8; ++k) {
        float v = o[k];
        v = v > 0.f ? v : __expf(v) - 1.f;   // ELU
        ov[k] = (_Float16)v;
    }
    if (half == 0)
        ((f16x8*)((_Float16*)out + (size_t)node * 256))[j] = ov;
}

// ---------------------------------------------------------------------------
// GATv2 gather, H=1 x C=64, fp16 in/out (no ELU). One wave per node,
// FOUR edges per wave-pass: quarter q4=l>>4 -> edge e+q4, lane group
// j=l&15 -> 4 channels j*4..+3 (8B loads). Unroll x2 (8 edges in flight).
// ---------------------------------------------------------------------------
__global__ __launch_bounds__(256) void gat_gather_h1(
        const __half* __restrict__ xl, const __half* __restrict__ xr,
        const float* __restrict__ att, const float* __restrict__ bias,
        const int* __restrict__ row_off, const int* __restrict__ esrc,
        __half* __restrict__ out, int n) {
    const float LOG2E = 1.44269504f;
    int wave = threadIdx.x >> 6;
    int lane = threadIdx.x & 63;
    int node = blockIdx.x * 4 + wave;
    if (node >= n) return;
    int q4 = lane >> 4;
    int j = lane & 15;

    uint2 xraw = ((const uint2*)(xr + (size_t)node * 64))[j];
    f16x2 xrv[2] = {*(const f16x2*)&xraw.x, *(const f16x2*)&xraw.y};
    float4 av = *(const float4*)(att + j * 4);
    f16x2 atv[2] = {{(_Float16)(av.x * LOG2E), (_Float16)(av.y * LOG2E)},
                    {(_Float16)(av.z * LOG2E), (_Float16)(av.w * LOG2E)}};
    const f16x2 k02 = {(_Float16)0.2f, (_Float16)0.2f};

    f32x2 acc0[2] = {}, acc1[2] = {};
    float l0 = 0.f, l1 = 0.f;

    int e0 = row_off[node], e1 = row_off[node + 1];
    int elast = e1 - 1;

#define H1_BODY(EBASE, ACC, LSUM)                                             \
    {                                                                         \
        int idx_ = EBASE + q4;                                                \
        int s_ = esrc[min(idx_, elast)];                                      \
        uint2 raw_ = ((const uint2*)(xl + (size_t)s_ * 64))[j];               \
        f16x2 v0_ = *(const f16x2*)&raw_.x;                                   \
        f16x2 v1_ = *(const f16x2*)&raw_.y;                                   \
        f16x2 s0_ = v0_ + xrv[0], s1_ = v1_ + xrv[1];                         \
        f16x2 r0_ = __builtin_elementwise_max(s0_, s0_ * k02);                \
        f16x2 r1_ = __builtin_elementwise_max(s1_, s1_ * k02);                \
        float t_ = __builtin_amdgcn_fdot2(r0_, atv[0], 0.f, false);           \
        t_ = __builtin_amdgcn_fdot2(r1_, atv[1], t_, false);                  \
        t_ += __shfl_xor(t_, 1);                                              \
        t_ += __shfl_xor(t_, 2);                                              \
        t_ += __shfl_xor(t_, 4);                                              \
        t_ += __shfl_xor(t_, 8);                                              \
        float p_ = exp2f(t_);                                                 \
        p_ = (idx_ < e1) ? p_ : 0.f;                                          \
        LSUM += p_;                                                           \
        f32x2 pp_ = {p_, p_};                                                 \
        ACC[0] += pp_ * (f32x2){(float)v0_.x, (float)v0_.y};                  \
        ACC[1] += pp_ * (f32x2){(float)v1_.x, (float)v1_.y};                  \
    }

    for (int e = e0; e < e1; e += 8) {
        H1_BODY(e, acc0, l0)
        if (e + 4 < e1) H1_BODY(e + 4, acc1, l1)
    }
#undef H1_BODY

    f32x2 acc[2] = {acc0[0] + acc1[0], acc0[1] + acc1[1]};
    float L = l0 + l1;
#pragma unroll
    for (int k = 0; k < 2; ++k) {
        acc[k].x += __shfl_xor(acc[k].x, 16);
        acc[k].y += __shfl_xor(acc[k].y, 16);
        acc[k].x += __shfl_xor(acc[k].x, 32);
        acc[k].y += __shfl_xor(acc[k].y, 32);
    }
    L += __shfl_xor(L, 16);
    L += __shfl_xor(L, 32);

    float inv = 1.f / (L + 1e-16f);
    float4 bv = *(const float4*)(bias + j * 4);
    f16x4 ov = {(_Float16)(acc[0].x * inv + bv.x),
                (_Float16)(acc[0].y * inv + bv.y),
                (_Float16)(acc[1].x * inv + bv.z),
                (_Float16)(acc[1].y * inv + bv.w)};
    if (q4 == 0)
        ((f16x4*)((_Float16*)out + (size_t)node * 64))[j] = ov;
}

// ---------------------------------------------------------------------------
extern "C" void kernel_launch(void* const* d_in, const int* in_sizes, int n_in,
                              void* d_out, int out_size, void* d_ws, size_t ws_size,
                              hipStream_t stream) {
    const float* x    = (const float*)d_in[0];
    const float* Wl1  = (const float*)d_in[1];
    const float* Wr1  = (const float*)d_in[2];
    const float* att1 = (const float*)d_in[3];
    const float* b1   = (const float*)d_in[4];
    const float* Wl2  = (const float*)d_in[5];
    const float* Wr2  = (const float*)d_in[6];
    const float* att2 = (const float*)d_in[7];
    const float* b2   = (const float*)d_in[8];
    const float* Wl3  = (const float*)d_in[9];
    const float* Wr3  = (const float*)d_in[10];
    const float* att3 = (const float*)d_in[11];
    const float* b3   = (const float*)d_in[12];
    const float* Wlin = (const float*)d_in[13];
    const float* blin = (const float*)d_in[14];
    const int*   ei   = (const int*)d_in[15];
    const int* src = ei;
    const int* dst = ei + EE;

    const int N = NN, E = EE;

    __half* xf = (__half*)d_ws;                 // N*128
    __half* xl = xf + (size_t)N * 128;          // N*256
    __half* xr = xl + (size_t)N * 256;          // N*256
    __half* H  = xr + (size_t)N * 256;          // N*256
    __half* G  = H + (size_t)N * 256;           // N*64
    __half* w1 = G + (size_t)N * 64;            // 65536  [512][128]
    __half* w2 = w1 + 65536;                    // 131072 [512][256]
    __half* w3 = w2 + 131072;                   // 32768  [128][256]
    __half* w4 = w3 + 32768;                    // 4096   [64][64]
    int* row_off = (int*)(w4 + 4096);           // N+1
    int* tmp     = row_off + (N + 1);           // 2N (counts | cursor)
    int* esrc    = tmp + 2 * N;                 // E

    // --- build CSR by dst (counts+cursor zeroed in ONE memset) ---
    hipMemsetAsync(tmp, 0, (size_t)2 * N * sizeof(int), stream);
    hist_kernel<<<1024, 256, 0, stream>>>(dst, tmp, E);
    scan_kernel<<<1, 1024, 0, stream>>>(tmp, row_off, N);
    scatter_kernel<<<1024, 256, 0, stream>>>(src, dst, row_off, tmp + N, esrc, E);

    // --- weights + x -> fp16 (one launch) ---
    int n4x = N * 128 / 4;
    prep_all<<<(233472 + n4x + 255) / 256, 256, 0, stream>>>(
        Wl1, Wr1, Wl2, Wr2, Wl3, Wr3, Wlin, w1, w2, w3, w4, x, xf, n4x);

    int nTiles = (N + 63) / 64;
    int gatherBlocks = (N + 3) / 4;

    // --- layer 1: xf[128] @ w1 -> xl,xr fp16 ---
    gemm_ws<4, 2><<<dim3(64, 4), 512, 0, stream>>>(
        xf, w1, N, nTiles, 512, 256, xl, xr, nullptr, nullptr);
    gat_gather_h4<<<gatherBlocks, 256, 0, stream>>>(xl, xr, att1, b1, row_off, esrc, H, N);

    // --- layer 2: H[256] @ w2 -> xl,xr ---
    gemm_ws<8, 2><<<dim3(64, 4), 512, 0, stream>>>(
        H, w2, N, nTiles, 512, 256, xl, xr, nullptr, nullptr);
    gat_gather_h4<<<gatherBlocks, 256, 0, stream>>>(xl, xr, att2, b2, row_off, esrc, H, N);

    // --- layer 3: H[256] @ w3 -> xl,xr ([N][64] each) ---
    gemm_ws<8, 2><<<dim3(256, 1), 512, 0, stream>>>(
        H, w3, N, nTiles, 128, 64, xl, xr, nullptr, nullptr);
    gat_gather_h1<<<gatherBlocks, 256, 0, stream>>>(xl, xr, att3, b3, row_off, esrc, G, N);

    // --- final: G[64] @ w4 + blin -> d_out fp32 ---
    gemm_ws<2, 1><<<dim3(512, 1), 256, 0, stream>>>(
        G, w4, N, nTiles, 64, 64, nullptr, nullptr, (float*)d_out, blin);
}